// Round 3
// baseline (1131.566 us; speedup 1.0000x reference)
//
#include <hip/hip_runtime.h>
#include <hip/hip_bf16.h>

#define NN 50000
#define NE 800000

// ---------------- edge_index width detection + normalization ----------------
// If edge_index survived as int64, every odd 32-bit word is 0 (values in [0,5e4)).
// Flag: 1 if int64, 0 if int32.

__global__ __launch_bounds__(64) void detect_idx(const int* __restrict__ ei, int* flag) {
  __shared__ int nz;
  if (threadIdx.x == 0) nz = 0;
  __syncthreads();
  int v = ei[2 * threadIdx.x + 1];   // odd words 1,3,...,127
  if (v != 0) atomicAdd(&nz, 1);
  __syncthreads();
  if (threadIdx.x == 0) *flag = (nz == 0) ? 1 : 0;
}

__global__ __launch_bounds__(256) void norm_idx(const int* __restrict__ ei,
    const int* __restrict__ flag, int* __restrict__ srcN, int* __restrict__ dstN, int e) {
  int i = blockIdx.x * 256 + threadIdx.x;
  if (i >= e) return;
  if (*flag) {                       // int64 layout: element j at words 2j (lo)
    srcN[i] = ei[2 * i];
    dstN[i] = ei[2 * (e + i)];
  } else {                           // int32 layout
    srcN[i] = ei[i];
    dstN[i] = ei[e + i];
  }
}

// ---------------- graph preprocessing (once per call) ----------------

__global__ __launch_bounds__(256) void prep_init(float* deg, int* cnt, int n) {
  int i = blockIdx.x * 256 + threadIdx.x;
  if (i < n) { deg[i] = 1.0f; cnt[i] = 0; }   // self-loop weight 1 in degree
}

__global__ __launch_bounds__(256) void prep_hist(const int* __restrict__ dst,
    const float* __restrict__ ew, float* deg, int* cnt, int e) {
  int i = blockIdx.x * 256 + threadIdx.x;
  if (i < e) {
    int d = dst[i];
    atomicAdd(&deg[d], ew[i]);
    atomicAdd(&cnt[d], 1);
  }
}

__global__ __launch_bounds__(256) void prep_dis(const float* __restrict__ deg,
    float* dis, int* cursor, int n) {
  int i = blockIdx.x * 256 + threadIdx.x;
  if (i < n) {
    float d = deg[i];
    dis[i] = (d > 0.f) ? rsqrtf(d) : 0.f;
    cursor[i] = 0;
  }
}

// single-block chunked Hillis-Steele exclusive scan of cnt -> rowstart[n+1]
__global__ __launch_bounds__(1024) void prep_scan(const int* __restrict__ cnt,
    int* __restrict__ rowstart, int n) {
  __shared__ int buf[1024];
  __shared__ int carry_s;
  int t = threadIdx.x;
  if (t == 0) carry_s = 0;
  __syncthreads();
  for (int base = 0; base < n; base += 1024) {
    int idx = base + t;
    int v = (idx < n) ? cnt[idx] : 0;
    buf[t] = v;
    __syncthreads();
    for (int off = 1; off < 1024; off <<= 1) {
      int x = (t >= off) ? buf[t - off] : 0;
      __syncthreads();
      buf[t] += x;
      __syncthreads();
    }
    int carry = carry_s;
    if (idx < n) rowstart[idx] = carry + buf[t] - v;
    __syncthreads();
    if (t == 0) carry_s = carry + buf[1023];
    __syncthreads();
  }
  if (t == 0) rowstart[n] = carry_s;
}

__global__ __launch_bounds__(256) void prep_scatter(const int* __restrict__ src,
    const int* __restrict__ dst, const float* __restrict__ ew,
    const float* __restrict__ dis,
    const int* __restrict__ rowstart, int* __restrict__ cursor,
    int* __restrict__ esrc, float* __restrict__ enorm, int e) {
  int i = blockIdx.x * 256 + threadIdx.x;
  if (i >= e) return;
  int d = dst[i];
  int s = src[i];
  int pos = rowstart[d] + atomicAdd(&cursor[d], 1);
  esrc[pos] = s;
  enorm[pos] = dis[s] * ew[i] * dis[d];
}

// ---------------- per-layer: fp32 tiled GEMM  XW = H @ W (128x128) ----------------

__global__ __launch_bounds__(256) void gemm128(const float* __restrict__ H,
    const float* __restrict__ W, float* __restrict__ XW, int M) {
  __shared__ float Ha[32][132];  // [k][m], padded
  __shared__ float Wa[32][132];  // [k][n], padded
  int t = threadIdx.x;
  int tx = t & 15, ty = t >> 4;
  int row0 = blockIdx.x * 128;
  float acc[8][8];
#pragma unroll
  for (int j = 0; j < 8; ++j)
#pragma unroll
    for (int i = 0; i < 8; ++i) acc[j][i] = 0.f;
  for (int kt = 0; kt < 128; kt += 32) {
#pragma unroll
    for (int p = 0; p < 4; ++p) {
      int lin = (p * 256 + t) * 4;       // 0..4095 over 128 rows x 32 k
      int m = lin >> 5, k = lin & 31;
      float4 v = make_float4(0.f, 0.f, 0.f, 0.f);
      int row = row0 + m;
      if (row < M) v = *(const float4*)(H + (size_t)row * 128 + kt + k);
      Ha[k + 0][m] = v.x;
      Ha[k + 1][m] = v.y;
      Ha[k + 2][m] = v.z;
      Ha[k + 3][m] = v.w;
    }
#pragma unroll
    for (int p = 0; p < 2; ++p) {
      int lin = (p * 256 + t) * 8;       // 0..4095 over 32 k x 128 n
      int k = lin >> 7, nn = lin & 127;
      const float* wp = W + (kt + k) * 128 + nn;
      *(float4*)&Wa[k][nn]     = *(const float4*)(wp);
      *(float4*)&Wa[k][nn + 4] = *(const float4*)(wp + 4);
    }
    __syncthreads();
#pragma unroll
    for (int kk = 0; kk < 32; ++kk) {
      float a[8], b[8];
      *(float4*)&a[0] = *(const float4*)&Ha[kk][ty * 8];
      *(float4*)&a[4] = *(const float4*)&Ha[kk][ty * 8 + 4];
      *(float4*)&b[0] = *(const float4*)&Wa[kk][tx * 8];
      *(float4*)&b[4] = *(const float4*)&Wa[kk][tx * 8 + 4];
#pragma unroll
      for (int j = 0; j < 8; ++j)
#pragma unroll
        for (int i = 0; i < 8; ++i) acc[j][i] = fmaf(a[j], b[i], acc[j][i]);
    }
    __syncthreads();
  }
#pragma unroll
  for (int j = 0; j < 8; ++j) {
    int row = row0 + ty * 8 + j;
    if (row < M) {
      *(float4*)(XW + (size_t)row * 128 + tx * 8)     = make_float4(acc[j][0], acc[j][1], acc[j][2], acc[j][3]);
      *(float4*)(XW + (size_t)row * 128 + tx * 8 + 4) = make_float4(acc[j][4], acc[j][5], acc[j][6], acc[j][7]);
    }
  }
}

// ---------------- per-layer: CSR aggregation + bias + relu (one wave per node) ----------------

__global__ __launch_bounds__(256) void agg_csr(const float* __restrict__ XW,
    const int* __restrict__ rowstart, const int* __restrict__ esrc,
    const float* __restrict__ enorm, const float* __restrict__ dis,
    const float* __restrict__ bias, float* __restrict__ Hout,
    int n) {
  int w = (blockIdx.x * 256 + threadIdx.x) >> 6;  // node index
  int lane = threadIdx.x & 63;
  if (w >= n) return;
  float d = dis[w];
  float d2 = d * d;                     // self-loop norm = dis^2 * 1.0
  const float* srow = XW + (size_t)w * 128;
  float a0 = d2 * srow[lane];
  float a1 = d2 * srow[64 + lane];
  int p1 = rowstart[w + 1];
  for (int p = rowstart[w]; p < p1; ++p) {
    int s = esrc[p];
    float wt = enorm[p];
    const float* row = XW + (size_t)s * 128;
    a0 = fmaf(wt, row[lane], a0);
    a1 = fmaf(wt, row[64 + lane], a1);
  }
  a0 += bias[lane];
  a1 += bias[64 + lane];
  a0 = fmaxf(a0, 0.f);
  a1 = fmaxf(a1, 0.f);
  Hout[(size_t)w * 128 + lane] = a0;
  Hout[(size_t)w * 128 + 64 + lane] = a1;
}

// ---------------- final layer: H @ W8 (128x2), aggregate, +b8, store fp32 ----------------

__global__ __launch_bounds__(256) void gemm_w8(const float* __restrict__ H,
    const float* __restrict__ W8, float* __restrict__ XW2, int n) {
  __shared__ float w[256];
  int t = threadIdx.x;
  w[t] = W8[t];
  __syncthreads();
  int r = blockIdx.x * 256 + t;
  if (r >= n) return;
  float a0 = 0.f, a1 = 0.f;
  const float* h = H + (size_t)r * 128;
#pragma unroll
  for (int k = 0; k < 128; k += 4) {
    float4 v = *(const float4*)(h + k);
    a0 += v.x * w[2 * k + 0] + v.y * w[2 * k + 2] + v.z * w[2 * k + 4] + v.w * w[2 * k + 6];
    a1 += v.x * w[2 * k + 1] + v.y * w[2 * k + 3] + v.z * w[2 * k + 5] + v.w * w[2 * k + 7];
  }
  XW2[r * 2 + 0] = a0;
  XW2[r * 2 + 1] = a1;
}

__global__ __launch_bounds__(256) void agg_final(const float* __restrict__ XW2,
    const int* __restrict__ rowstart, const int* __restrict__ esrc,
    const float* __restrict__ enorm, const float* __restrict__ dis,
    const float* __restrict__ b8, float* __restrict__ out, int n) {
  int i = blockIdx.x * 256 + threadIdx.x;
  if (i >= n) return;
  float d = dis[i], d2 = d * d;
  float a0 = d2 * XW2[i * 2 + 0];
  float a1 = d2 * XW2[i * 2 + 1];
  int p1 = rowstart[i + 1];
  for (int p = rowstart[i]; p < p1; ++p) {
    int s = esrc[p];
    float wt = enorm[p];
    a0 = fmaf(wt, XW2[s * 2 + 0], a0);
    a1 = fmaf(wt, XW2[s * 2 + 1], a1);
  }
  out[i * 2 + 0] = a0 + b8[0];   // fp32 output — reference returns float32
  out[i * 2 + 1] = a1 + b8[1];
}

// ---------------- launcher ----------------

extern "C" void kernel_launch(void* const* d_in, const int* in_sizes, int n_in,
                              void* d_out, int out_size, void* d_ws, size_t ws_size,
                              hipStream_t stream) {
  (void)in_sizes; (void)n_in; (void)out_size; (void)ws_size;
  const int n = NN, e = NE;
  const float* x  = (const float*)d_in[0];
  const int*   ei = (const int*)d_in[1];
  const float* ea = (const float*)d_in[2];
  const float* W1 = (const float*)d_in[3];
  const float* b1 = (const float*)d_in[4];
  const float* Wm = (const float*)d_in[5];
  const float* bm = (const float*)d_in[6];
  const float* W8 = (const float*)d_in[7];
  const float* b8 = (const float*)d_in[8];
  float* out = (float*)d_out;

  char* w = (char*)d_ws;
  int*   flag  = (int*)w;   w += 256;
  int*   srcN  = (int*)w;   w += (size_t)e * 4;
  int*   dstN  = (int*)w;   w += (size_t)e * 4;
  float* deg   = (float*)w; w += (size_t)n * 4;
  float* dis   = (float*)w; w += (size_t)n * 4;
  int*   cnt   = (int*)w;   w += (size_t)n * 4;
  int*   cursor= (int*)w;   w += (size_t)n * 4;
  int*   rowst = (int*)w;   w += (((size_t)(n + 1) * 4 + 255) & ~(size_t)255);
  int*   esrc  = (int*)w;   w += (size_t)e * 4;
  float* enorm = (float*)w; w += (size_t)e * 4;
  float* Hb    = (float*)w; w += (size_t)n * 128 * 4;
  float* XW    = (float*)w; w += (size_t)n * 128 * 4;

  const int GN = (n + 255) / 256;
  const int GE = (e + 255) / 256;

  detect_idx<<<1, 64, 0, stream>>>(ei, flag);
  norm_idx<<<GE, 256, 0, stream>>>(ei, flag, srcN, dstN, e);
  prep_init<<<GN, 256, 0, stream>>>(deg, cnt, n);
  prep_hist<<<GE, 256, 0, stream>>>(dstN, ea, deg, cnt, e);
  prep_dis<<<GN, 256, 0, stream>>>(deg, dis, cursor, n);
  prep_scan<<<1, 1024, 0, stream>>>(cnt, rowst, n);
  prep_scatter<<<GE, 256, 0, stream>>>(srcN, dstN, ea, dis, rowst, cursor, esrc, enorm, e);

  // layer 1: reads x directly (x is fp32 [N,128])
  gemm128<<<(n + 127) / 128, 256, 0, stream>>>(x, W1, XW, n);
  agg_csr<<<(n * 64 + 255) / 256, 256, 0, stream>>>(XW, rowst, esrc, enorm, dis, b1, Hb, n);

  for (int l = 1; l < 7; ++l) {
    const float* Wl = Wm + (size_t)(l - 1) * 128 * 128;
    const float* bl = bm + (size_t)(l - 1) * 128;
    gemm128<<<(n + 127) / 128, 256, 0, stream>>>(Hb, Wl, XW, n);
    agg_csr<<<(n * 64 + 255) / 256, 256, 0, stream>>>(XW, rowst, esrc, enorm, dis, bl, Hb, n);
  }
  gemm_w8<<<GN, 256, 0, stream>>>(Hb, W8, XW, n);
  agg_final<<<GN, 256, 0, stream>>>(XW, rowst, esrc, enorm, dis, b8, out, n);
}

// Round 4
// 924.644 us; speedup vs baseline: 1.2238x; 1.2238x over previous
//
#include <hip/hip_runtime.h>
#include <hip/hip_bf16.h>

#define NN 50000
#define NE 800000
#define MP 50048            // NN padded to multiple of 64
#define SCAN_NB 196         // ceil(NN/256)

typedef __bf16 bf16x8 __attribute__((ext_vector_type(8)));
typedef float f32x4 __attribute__((ext_vector_type(4)));

static __device__ __forceinline__ float b2f(unsigned short u) {
  union { unsigned int i; float f; } v; v.i = ((unsigned int)u) << 16; return v.f;
}
static __device__ __forceinline__ unsigned short f2b(float f) {
  __hip_bfloat16 h = __float2bfloat16(f);
  union { __hip_bfloat16 h; unsigned short u; } v; v.h = h; return v.u;
}

// ---------------- edge_index width detection ----------------
__global__ __launch_bounds__(64) void detect_idx(const int* __restrict__ ei, int* flag) {
  __shared__ int nz;
  if (threadIdx.x == 0) nz = 0;
  __syncthreads();
  if (ei[2 * threadIdx.x + 1] != 0) atomicAdd(&nz, 1);
  __syncthreads();
  if (threadIdx.x == 0) *flag = (nz == 0) ? 1 : 0;   // 1 => int64 layout
}

static __device__ __forceinline__ int get_src(const int* ei, int f, int i) {
  return f ? ei[2 * i] : ei[i];
}
static __device__ __forceinline__ int get_dst(const int* ei, int f, int i) {
  return f ? ei[2 * (NE + i)] : ei[NE + i];
}

// ---------------- graph preprocessing ----------------
__global__ __launch_bounds__(256) void prep_init(float* deg, int* cnt, int n) {
  int i = blockIdx.x * 256 + threadIdx.x;
  if (i < n) { deg[i] = 1.0f; cnt[i] = 0; }
}

__global__ __launch_bounds__(256) void prep_hist(const int* __restrict__ ei,
    const int* __restrict__ flag, const float* __restrict__ ew,
    float* deg, int* cnt, int e) {
  int i = blockIdx.x * 256 + threadIdx.x;
  if (i < e) {
    int f = *flag;
    int d = get_dst(ei, f, i);
    atomicAdd(&deg[d], ew[i]);
    atomicAdd(&cnt[d], 1);
  }
}

__global__ __launch_bounds__(256) void prep_dis(const float* __restrict__ deg,
    float* dis, int* cursor, int n) {
  int i = blockIdx.x * 256 + threadIdx.x;
  if (i < n) {
    float d = deg[i];
    dis[i] = (d > 0.f) ? rsqrtf(d) : 0.f;
    cursor[i] = 0;
  }
}

// ---- 3-kernel scan: block partials -> tops scan -> apply ----
__global__ __launch_bounds__(256) void scan_part(const int* __restrict__ cnt,
    int* __restrict__ part, int n) {
  __shared__ int sb[256];
  int t = threadIdx.x, i = blockIdx.x * 256 + t;
  sb[t] = (i < n) ? cnt[i] : 0;
  __syncthreads();
  for (int off = 128; off > 0; off >>= 1) {
    if (t < off) sb[t] += sb[t + off];
    __syncthreads();
  }
  if (t == 0) part[blockIdx.x] = sb[0];
}

__global__ __launch_bounds__(256) void scan_tops(const int* __restrict__ part,
    int* __restrict__ partoff, int* __restrict__ rowstart, int n, int e, int nb) {
  __shared__ int sb[256];
  int t = threadIdx.x;
  int v = (t < nb) ? part[t] : 0;
  sb[t] = v;
  __syncthreads();
  for (int off = 1; off < 256; off <<= 1) {
    int x = (t >= off) ? sb[t - off] : 0;
    __syncthreads();
    sb[t] += x;
    __syncthreads();
  }
  if (t < nb) partoff[t] = sb[t] - v;   // exclusive block offsets
  if (t == 0) rowstart[n] = e;
}

__global__ __launch_bounds__(256) void scan_apply(const int* __restrict__ cnt,
    const int* __restrict__ partoff, int* __restrict__ rowstart, int n) {
  __shared__ int sb[256];
  int t = threadIdx.x, i = blockIdx.x * 256 + t;
  int v = (i < n) ? cnt[i] : 0;
  sb[t] = v;
  __syncthreads();
  for (int off = 1; off < 256; off <<= 1) {
    int x = (t >= off) ? sb[t - off] : 0;
    __syncthreads();
    sb[t] += x;
    __syncthreads();
  }
  if (i < n) rowstart[i] = partoff[blockIdx.x] + sb[t] - v;
}

__global__ __launch_bounds__(256) void prep_scatter(const int* __restrict__ ei,
    const int* __restrict__ flag, const float* __restrict__ ew,
    const float* __restrict__ dis, const int* __restrict__ rowstart,
    int* __restrict__ cursor, int* __restrict__ esrc, float* __restrict__ enorm, int e) {
  int i = blockIdx.x * 256 + threadIdx.x;
  if (i >= e) return;
  int f = *flag;
  int d = get_dst(ei, f, i);
  int s = get_src(ei, f, i);
  int pos = rowstart[d] + atomicAdd(&cursor[d], 1);
  esrc[pos] = s;
  enorm[pos] = dis[s] * ew[i] * dis[d];
}

// ---------------- input conversions (once) ----------------
// x fp32 -> hi/lo bf16 pair arrays, zero-padded rows NN..MP
__global__ __launch_bounds__(256) void cvt_x(const float* __restrict__ x,
    unsigned short* __restrict__ Hh, unsigned short* __restrict__ Hl,
    int total, int valid) {
  int i = blockIdx.x * 256 + threadIdx.x;   // element index (x4)
  int b = i * 4;
  if (b >= total) return;
  ushort4 oh, ol;
  float v0 = (b + 0 < valid) ? x[b + 0] : 0.f;
  float v1 = (b + 1 < valid) ? x[b + 1] : 0.f;
  float v2 = (b + 2 < valid) ? x[b + 2] : 0.f;
  float v3 = (b + 3 < valid) ? x[b + 3] : 0.f;
  oh.x = f2b(v0); ol.x = f2b(v0 - b2f(oh.x));
  oh.y = f2b(v1); ol.y = f2b(v1 - b2f(oh.y));
  oh.z = f2b(v2); ol.z = f2b(v2 - b2f(oh.z));
  oh.w = f2b(v3); ol.w = f2b(v3 - b2f(oh.w));
  *(ushort4*)(Hh + b) = oh;
  *(ushort4*)(Hl + b) = ol;
}

// weights [k][n] 128x128 fp32 (7 layers) -> transposed [n][k] hi/lo bf16
__global__ __launch_bounds__(256) void cvt_w(const float* __restrict__ W1,
    const float* __restrict__ Wm, unsigned short* __restrict__ Wth,
    unsigned short* __restrict__ Wtl) {
  int i = blockIdx.x * 256 + threadIdx.x;           // 7*16384
  if (i >= 7 * 16384) return;
  int l = i >> 14, r = i & 16383;
  int k = r >> 7, n = r & 127;
  const float* src = (l == 0) ? W1 : (Wm + (size_t)(l - 1) * 16384);
  float v = src[k * 128 + n];
  unsigned short h = f2b(v);
  int o = l * 16384 + n * 128 + k;
  Wth[o] = h;
  Wtl[o] = f2b(v - b2f(h));
}

// ---------------- MFMA split-bf16 GEMM: XW[MP,128] = H @ W ----------------
__global__ __launch_bounds__(256) void gemm_mfma(
    const unsigned short* __restrict__ Hh, const unsigned short* __restrict__ Hl,
    const unsigned short* __restrict__ Bh, const unsigned short* __restrict__ Bl,
    float* __restrict__ XW) {
  __shared__ unsigned short As[2][64][136];   // [hi/lo][row][k], row stride 272B
  int t = threadIdx.x;
  int rowbase = blockIdx.x * 64;
  {
    int r = t >> 2, ks = (t & 3) * 32;
    const uint4* gh = (const uint4*)(Hh + (size_t)(rowbase + r) * 128 + ks);
    const uint4* gl = (const uint4*)(Hl + (size_t)(rowbase + r) * 128 + ks);
    uint4* sh = (uint4*)&As[0][r][ks];
    uint4* sl = (uint4*)&As[1][r][ks];
#pragma unroll
    for (int i = 0; i < 4; ++i) { sh[i] = gh[i]; sl[i] = gl[i]; }
  }
  __syncthreads();
  int lane = t & 63;
  int wv = t >> 6;
  int m16 = lane & 15;
  int quad = lane >> 4;
  int arow = wv * 16 + m16;
  f32x4 acc[8];
#pragma unroll
  for (int i = 0; i < 8; ++i) acc[i] = (f32x4){0.f, 0.f, 0.f, 0.f};
#pragma unroll
  for (int kc = 0; kc < 4; ++kc) {
    int k0 = kc * 32 + quad * 8;
    bf16x8 ah = *(const bf16x8*)&As[0][arow][k0];
    bf16x8 al = *(const bf16x8*)&As[1][arow][k0];
#pragma unroll
    for (int tt = 0; tt < 8; ++tt) {
      int n = tt * 16 + m16;
      bf16x8 bh = *(const bf16x8*)(Bh + n * 128 + k0);
      bf16x8 bl = *(const bf16x8*)(Bl + n * 128 + k0);
      acc[tt] = __builtin_amdgcn_mfma_f32_16x16x32_bf16(ah, bh, acc[tt], 0, 0, 0);
      acc[tt] = __builtin_amdgcn_mfma_f32_16x16x32_bf16(ah, bl, acc[tt], 0, 0, 0);
      acc[tt] = __builtin_amdgcn_mfma_f32_16x16x32_bf16(al, bh, acc[tt], 0, 0, 0);
    }
  }
  // C/D layout: col = lane&15, row = quad*4 + reg
#pragma unroll
  for (int tt = 0; tt < 8; ++tt) {
#pragma unroll
    for (int r = 0; r < 4; ++r) {
      int grow = rowbase + wv * 16 + quad * 4 + r;
      XW[(size_t)grow * 128 + tt * 16 + m16] = acc[tt][r];
    }
  }
}

// ---------------- CSR aggregation + bias + relu -> bf16 hi/lo H ----------------
__global__ __launch_bounds__(256) void agg_csr(const float* __restrict__ XW,
    const int* __restrict__ rowstart, const int* __restrict__ esrc,
    const float* __restrict__ enorm, const float* __restrict__ dis,
    const float* __restrict__ bias,
    unsigned short* __restrict__ Hh, unsigned short* __restrict__ Hl, int n) {
  int w = (blockIdx.x * 256 + threadIdx.x) >> 6;
  int l = threadIdx.x & 63;
  if (w >= n) return;
  float dd = dis[w];
  float d2 = dd * dd;
  float2 s = ((const float2*)(XW + (size_t)w * 128))[l];
  float2 A0 = make_float2(d2 * s.x, d2 * s.y);
  float2 A1 = make_float2(0.f, 0.f), A2 = make_float2(0.f, 0.f), A3 = make_float2(0.f, 0.f);
  int p = rowstart[w], p1 = rowstart[w + 1];
  for (; p + 4 <= p1; p += 4) {
    int s0 = esrc[p], s1 = esrc[p + 1], s2 = esrc[p + 2], s3 = esrc[p + 3];
    float w0 = enorm[p], w1 = enorm[p + 1], w2 = enorm[p + 2], w3 = enorm[p + 3];
    float2 r0 = ((const float2*)(XW + (size_t)s0 * 128))[l];
    float2 r1 = ((const float2*)(XW + (size_t)s1 * 128))[l];
    float2 r2 = ((const float2*)(XW + (size_t)s2 * 128))[l];
    float2 r3 = ((const float2*)(XW + (size_t)s3 * 128))[l];
    A0.x = fmaf(w0, r0.x, A0.x); A0.y = fmaf(w0, r0.y, A0.y);
    A1.x = fmaf(w1, r1.x, A1.x); A1.y = fmaf(w1, r1.y, A1.y);
    A2.x = fmaf(w2, r2.x, A2.x); A2.y = fmaf(w2, r2.y, A2.y);
    A3.x = fmaf(w3, r3.x, A3.x); A3.y = fmaf(w3, r3.y, A3.y);
  }
  for (; p < p1; ++p) {
    int s0 = esrc[p];
    float w0 = enorm[p];
    float2 r0 = ((const float2*)(XW + (size_t)s0 * 128))[l];
    A0.x = fmaf(w0, r0.x, A0.x); A0.y = fmaf(w0, r0.y, A0.y);
  }
  float2 b = ((const float2*)bias)[l];
  float vx = fmaxf(A0.x + A1.x + A2.x + A3.x + b.x, 0.f);
  float vy = fmaxf(A0.y + A1.y + A2.y + A3.y + b.y, 0.f);
  ushort2 oh, ol;
  oh.x = f2b(vx); ol.x = f2b(vx - b2f(oh.x));
  oh.y = f2b(vy); ol.y = f2b(vy - b2f(oh.y));
  ((ushort2*)(Hh + (size_t)w * 128))[l] = oh;
  ((ushort2*)(Hl + (size_t)w * 128))[l] = ol;
}

// ---------------- final layer ----------------
__global__ __launch_bounds__(256) void gemm_w8(const unsigned short* __restrict__ Hh,
    const unsigned short* __restrict__ Hl, const float* __restrict__ W8,
    float* __restrict__ XW2, int n) {
  __shared__ float w[256];
  int t = threadIdx.x;
  w[t] = W8[t];
  __syncthreads();
  int r = blockIdx.x * 256 + t;
  if (r >= n) return;
  const unsigned short* hh = Hh + (size_t)r * 128;
  const unsigned short* hl = Hl + (size_t)r * 128;
  float a0 = 0.f, a1 = 0.f;
#pragma unroll
  for (int k = 0; k < 128; k += 4) {
    ushort4 uh = *(const ushort4*)(hh + k);
    ushort4 ul = *(const ushort4*)(hl + k);
    float h0 = b2f(uh.x) + b2f(ul.x);
    float h1 = b2f(uh.y) + b2f(ul.y);
    float h2 = b2f(uh.z) + b2f(ul.z);
    float h3 = b2f(uh.w) + b2f(ul.w);
    a0 += h0 * w[2 * k + 0] + h1 * w[2 * k + 2] + h2 * w[2 * k + 4] + h3 * w[2 * k + 6];
    a1 += h0 * w[2 * k + 1] + h1 * w[2 * k + 3] + h2 * w[2 * k + 5] + h3 * w[2 * k + 7];
  }
  XW2[r * 2 + 0] = a0;
  XW2[r * 2 + 1] = a1;
}

__global__ __launch_bounds__(256) void agg_final(const float* __restrict__ XW2,
    const int* __restrict__ rowstart, const int* __restrict__ esrc,
    const float* __restrict__ enorm, const float* __restrict__ dis,
    const float* __restrict__ b8, float* __restrict__ out, int n) {
  int i = blockIdx.x * 256 + threadIdx.x;
  if (i >= n) return;
  float d = dis[i], d2 = d * d;
  float a0 = d2 * XW2[i * 2 + 0];
  float a1 = d2 * XW2[i * 2 + 1];
  int p1 = rowstart[i + 1];
  for (int p = rowstart[i]; p < p1; ++p) {
    int s = esrc[p];
    float wt = enorm[p];
    a0 = fmaf(wt, XW2[s * 2 + 0], a0);
    a1 = fmaf(wt, XW2[s * 2 + 1], a1);
  }
  out[i * 2 + 0] = a0 + b8[0];
  out[i * 2 + 1] = a1 + b8[1];
}

// ---------------- launcher ----------------
static inline char* alignp(char* p) {
  return (char*)(((uintptr_t)p + 255) & ~(uintptr_t)255);
}

extern "C" void kernel_launch(void* const* d_in, const int* in_sizes, int n_in,
                              void* d_out, int out_size, void* d_ws, size_t ws_size,
                              hipStream_t stream) {
  (void)in_sizes; (void)n_in; (void)out_size; (void)ws_size;
  const int n = NN, e = NE;
  const float* x  = (const float*)d_in[0];
  const int*   ei = (const int*)d_in[1];
  const float* ea = (const float*)d_in[2];
  const float* W1 = (const float*)d_in[3];
  const float* b1 = (const float*)d_in[4];
  const float* Wm = (const float*)d_in[5];
  const float* bm = (const float*)d_in[6];
  const float* W8 = (const float*)d_in[7];
  const float* b8 = (const float*)d_in[8];
  float* out = (float*)d_out;

  char* w = (char*)d_ws;
  int*   flag   = (int*)w;            w = alignp(w + 4);
  int*   part   = (int*)w;            w = alignp(w + SCAN_NB * 4);
  int*   partoff= (int*)w;            w = alignp(w + SCAN_NB * 4);
  float* deg    = (float*)w;          w = alignp(w + (size_t)n * 4);
  float* dis    = (float*)w;          w = alignp(w + (size_t)n * 4);
  int*   cnt    = (int*)w;            w = alignp(w + (size_t)n * 4);
  int*   cursor = (int*)w;            w = alignp(w + (size_t)n * 4);
  int*   rowst  = (int*)w;            w = alignp(w + (size_t)(n + 1) * 4);
  int*   esrc   = (int*)w;            w = alignp(w + (size_t)e * 4);
  float* enorm  = (float*)w;          w = alignp(w + (size_t)e * 4);
  unsigned short* Hh  = (unsigned short*)w;  w = alignp(w + (size_t)MP * 128 * 2);
  unsigned short* Hl  = (unsigned short*)w;  w = alignp(w + (size_t)MP * 128 * 2);
  unsigned short* Wth = (unsigned short*)w;  w = alignp(w + (size_t)7 * 16384 * 2);
  unsigned short* Wtl = (unsigned short*)w;  w = alignp(w + (size_t)7 * 16384 * 2);
  float* XW   = (float*)w;            w = alignp(w + (size_t)MP * 128 * 4);
  float* XW2  = (float*)w;            w = alignp(w + (size_t)MP * 2 * 4);

  const int GN = (n + 255) / 256;
  const int GE = (e + 255) / 256;

  detect_idx<<<1, 64, 0, stream>>>(ei, flag);
  prep_init<<<GN, 256, 0, stream>>>(deg, cnt, n);
  prep_hist<<<GE, 256, 0, stream>>>(ei, flag, ea, deg, cnt, e);
  prep_dis<<<GN, 256, 0, stream>>>(deg, dis, cursor, n);
  scan_part<<<SCAN_NB, 256, 0, stream>>>(cnt, part, n);
  scan_tops<<<1, 256, 0, stream>>>(part, partoff, rowst, n, e, SCAN_NB);
  scan_apply<<<SCAN_NB, 256, 0, stream>>>(cnt, partoff, rowst, n);
  prep_scatter<<<GE, 256, 0, stream>>>(ei, flag, ea, dis, rowst, cursor, esrc, enorm, e);
  cvt_x<<<(MP * 128 / 4 + 255) / 256, 256, 0, stream>>>(x, Hh, Hl, MP * 128, n * 128);
  cvt_w<<<(7 * 16384 + 255) / 256, 256, 0, stream>>>(W1, Wm, Wth, Wtl);

  for (int l = 0; l < 7; ++l) {
    const unsigned short* Bh = Wth + (size_t)l * 16384;
    const unsigned short* Bl = Wtl + (size_t)l * 16384;
    const float* bl = (l == 0) ? b1 : bm + (size_t)(l - 1) * 128;
    gemm_mfma<<<MP / 64, 256, 0, stream>>>(Hh, Hl, Bh, Bl, XW);
    agg_csr<<<(n * 64 + 255) / 256, 256, 0, stream>>>(XW, rowst, esrc, enorm, dis, bl, Hh, Hl, n);
  }
  gemm_w8<<<GN, 256, 0, stream>>>(Hh, Hl, W8, XW2, n);
  agg_final<<<GN, 256, 0, stream>>>(XW2, rowst, esrc, enorm, dis, b8, out, n);
}

// Round 5
// 757.306 us; speedup vs baseline: 1.4942x; 1.2210x over previous
//
#include <hip/hip_runtime.h>
#include <hip/hip_bf16.h>
#include <hip/hip_fp16.h>

#define NN 50000
#define NE 800000
#define MP 50048            // NN padded to multiple of 64
#define SCAN_NB 196         // ceil(NN/256)

typedef __bf16 bf16x8 __attribute__((ext_vector_type(8)));
typedef float f32x4 __attribute__((ext_vector_type(4)));

static __device__ __forceinline__ float b2f(unsigned short u) {
  union { unsigned int i; float f; } v; v.i = ((unsigned int)u) << 16; return v.f;
}
static __device__ __forceinline__ unsigned short f2b(float f) {
  __hip_bfloat16 h = __float2bfloat16(f);
  union { __hip_bfloat16 h; unsigned short u; } v; v.h = h; return v.u;
}

// ---------------- edge_index width detection ----------------
__global__ __launch_bounds__(64) void detect_idx(const int* __restrict__ ei, int* flag) {
  __shared__ int nz;
  if (threadIdx.x == 0) nz = 0;
  __syncthreads();
  if (ei[2 * threadIdx.x + 1] != 0) atomicAdd(&nz, 1);
  __syncthreads();
  if (threadIdx.x == 0) *flag = (nz == 0) ? 1 : 0;   // 1 => int64 layout
}

static __device__ __forceinline__ int get_src(const int* ei, int f, int i) {
  return f ? ei[2 * i] : ei[i];
}
static __device__ __forceinline__ int get_dst(const int* ei, int f, int i) {
  return f ? ei[2 * (NE + i)] : ei[NE + i];
}

// ---------------- graph preprocessing ----------------
// dc[i]: high 32 = edge count, low 32 = fixed-point (2^-20) weighted degree
__global__ __launch_bounds__(256) void prep_init(unsigned long long* dc, int n) {
  int i = blockIdx.x * 256 + threadIdx.x;
  if (i < n) dc[i] = 1048576ull;   // self-loop weight 1.0, cnt 0
}

__global__ __launch_bounds__(256) void prep_hist(const int* __restrict__ ei,
    const int* __restrict__ flag, const float* __restrict__ ew,
    unsigned long long* dc, int e) {
  int i = blockIdx.x * 256 + threadIdx.x;
  if (i < e) {
    int f = *flag;
    int d = get_dst(ei, f, i);
    unsigned long long fx = (unsigned long long)(ew[i] * 1048576.0f + 0.5f);
    atomicAdd(&dc[d], (1ull << 32) | fx);
  }
}

__global__ __launch_bounds__(256) void prep_dis(const unsigned long long* __restrict__ dc,
    float* dis, int* cnt, int* cursor, int n) {
  int i = blockIdx.x * 256 + threadIdx.x;
  if (i < n) {
    unsigned long long v = dc[i];
    float d = (float)(unsigned int)(v & 0xffffffffull) * (1.0f / 1048576.0f);
    dis[i] = (d > 0.f) ? rsqrtf(d) : 0.f;
    cnt[i] = (int)(v >> 32);
    cursor[i] = 0;
  }
}

// ---- 3-kernel scan: block partials -> tops scan -> apply ----
__global__ __launch_bounds__(256) void scan_part(const int* __restrict__ cnt,
    int* __restrict__ part, int n) {
  __shared__ int sb[256];
  int t = threadIdx.x, i = blockIdx.x * 256 + t;
  sb[t] = (i < n) ? cnt[i] : 0;
  __syncthreads();
  for (int off = 128; off > 0; off >>= 1) {
    if (t < off) sb[t] += sb[t + off];
    __syncthreads();
  }
  if (t == 0) part[blockIdx.x] = sb[0];
}

__global__ __launch_bounds__(256) void scan_tops(const int* __restrict__ part,
    int* __restrict__ partoff, int* __restrict__ rowstart, int n, int e, int nb) {
  __shared__ int sb[256];
  int t = threadIdx.x;
  int v = (t < nb) ? part[t] : 0;
  sb[t] = v;
  __syncthreads();
  for (int off = 1; off < 256; off <<= 1) {
    int x = (t >= off) ? sb[t - off] : 0;
    __syncthreads();
    sb[t] += x;
    __syncthreads();
  }
  if (t < nb) partoff[t] = sb[t] - v;   // exclusive block offsets
  if (t == 0) rowstart[n] = e;
}

__global__ __launch_bounds__(256) void scan_apply(const int* __restrict__ cnt,
    const int* __restrict__ partoff, int* __restrict__ rowstart, int n) {
  __shared__ int sb[256];
  int t = threadIdx.x, i = blockIdx.x * 256 + t;
  int v = (i < n) ? cnt[i] : 0;
  sb[t] = v;
  __syncthreads();
  for (int off = 1; off < 256; off <<= 1) {
    int x = (t >= off) ? sb[t - off] : 0;
    __syncthreads();
    sb[t] += x;
    __syncthreads();
  }
  if (i < n) rowstart[i] = partoff[blockIdx.x] + sb[t] - v;
}

__global__ __launch_bounds__(256) void prep_scatter(const int* __restrict__ ei,
    const int* __restrict__ flag, const float* __restrict__ ew,
    const float* __restrict__ dis, const int* __restrict__ rowstart,
    int* __restrict__ cursor, int* __restrict__ esrc, float* __restrict__ enorm, int e) {
  int i = blockIdx.x * 256 + threadIdx.x;
  if (i >= e) return;
  int f = *flag;
  int d = get_dst(ei, f, i);
  int s = get_src(ei, f, i);
  int pos = rowstart[d] + atomicAdd(&cursor[d], 1);
  esrc[pos] = s;
  enorm[pos] = dis[s] * ew[i] * dis[d];
}

// ---------------- input conversions (once) ----------------
__global__ __launch_bounds__(256) void cvt_x(const float* __restrict__ x,
    unsigned short* __restrict__ Hh, unsigned short* __restrict__ Hl,
    int total, int valid) {
  int i = blockIdx.x * 256 + threadIdx.x;
  int b = i * 4;
  if (b >= total) return;
  ushort4 oh, ol;
  float v0 = (b + 0 < valid) ? x[b + 0] : 0.f;
  float v1 = (b + 1 < valid) ? x[b + 1] : 0.f;
  float v2 = (b + 2 < valid) ? x[b + 2] : 0.f;
  float v3 = (b + 3 < valid) ? x[b + 3] : 0.f;
  oh.x = f2b(v0); ol.x = f2b(v0 - b2f(oh.x));
  oh.y = f2b(v1); ol.y = f2b(v1 - b2f(oh.y));
  oh.z = f2b(v2); ol.z = f2b(v2 - b2f(oh.z));
  oh.w = f2b(v3); ol.w = f2b(v3 - b2f(oh.w));
  *(ushort4*)(Hh + b) = oh;
  *(ushort4*)(Hl + b) = ol;
}

// weights [k][n] 128x128 fp32 (7 layers) -> transposed [n][k] hi/lo bf16
__global__ __launch_bounds__(256) void cvt_w(const float* __restrict__ W1,
    const float* __restrict__ Wm, unsigned short* __restrict__ Wth,
    unsigned short* __restrict__ Wtl) {
  int i = blockIdx.x * 256 + threadIdx.x;           // 7*16384
  if (i >= 7 * 16384) return;
  int l = i >> 14, r = i & 16383;
  int k = r >> 7, n = r & 127;
  const float* src = (l == 0) ? W1 : (Wm + (size_t)(l - 1) * 16384);
  float v = src[k * 128 + n];
  unsigned short h = f2b(v);
  int o = l * 16384 + n * 128 + k;
  Wth[o] = h;
  Wtl[o] = f2b(v - b2f(h));
}

// ---------------- MFMA split-bf16 GEMM: XW[MP,128] (fp16) = H @ W ----------------
// A fragments straight from global (coalesced by MFMA layout); epilogue LDS
// transpose for coalesced fp16 stores. C[64][133]: 133%32=5 -> conflict-free-ish.
__global__ __launch_bounds__(256) void gemm_mfma(
    const unsigned short* __restrict__ Hh, const unsigned short* __restrict__ Hl,
    const unsigned short* __restrict__ Bh, const unsigned short* __restrict__ Bl,
    __half* __restrict__ XW) {
  __shared__ float C[64][133];
  int t = threadIdx.x;
  int lane = t & 63, wv = t >> 6;
  int m16 = lane & 15, quad = lane >> 4;
  int rowbase = blockIdx.x * 64;
  int arow = rowbase + wv * 16 + m16;
  f32x4 acc[8];
#pragma unroll
  for (int i = 0; i < 8; ++i) acc[i] = (f32x4){0.f, 0.f, 0.f, 0.f};
  const unsigned short* ph = Hh + (size_t)arow * 128 + quad * 8;
  const unsigned short* pl = Hl + (size_t)arow * 128 + quad * 8;
#pragma unroll
  for (int kc = 0; kc < 4; ++kc) {
    bf16x8 ah = *(const bf16x8*)(ph + kc * 32);
    bf16x8 al = *(const bf16x8*)(pl + kc * 32);
    int k0 = kc * 32 + quad * 8;
#pragma unroll
    for (int tt = 0; tt < 8; ++tt) {
      int nn = tt * 16 + m16;
      bf16x8 bh = *(const bf16x8*)(Bh + nn * 128 + k0);
      bf16x8 bl = *(const bf16x8*)(Bl + nn * 128 + k0);
      acc[tt] = __builtin_amdgcn_mfma_f32_16x16x32_bf16(ah, bh, acc[tt], 0, 0, 0);
      acc[tt] = __builtin_amdgcn_mfma_f32_16x16x32_bf16(ah, bl, acc[tt], 0, 0, 0);
      acc[tt] = __builtin_amdgcn_mfma_f32_16x16x32_bf16(al, bh, acc[tt], 0, 0, 0);
    }
  }
  // C/D layout: col = m16 (+tt*16), row = quad*4 + r (within wv's 16-row tile)
#pragma unroll
  for (int tt = 0; tt < 8; ++tt)
#pragma unroll
    for (int r = 0; r < 4; ++r)
      C[wv * 16 + quad * 4 + r][tt * 16 + m16] = acc[tt][r];
  __syncthreads();
  int rr = t >> 2;               // 0..63
  int cb = (t & 3) * 32;         // col base
  const float* crow = &C[rr][cb];
  __half2 o[16];
#pragma unroll
  for (int i = 0; i < 16; ++i) {
    __half2 h;
    h.x = __float2half_rn(crow[2 * i]);
    h.y = __float2half_rn(crow[2 * i + 1]);
    o[i] = h;
  }
  uint4* dst = (uint4*)(XW + (size_t)(rowbase + rr) * 128 + cb);
  dst[0] = ((const uint4*)o)[0];
  dst[1] = ((const uint4*)o)[1];
  dst[2] = ((const uint4*)o)[2];
  dst[3] = ((const uint4*)o)[3];
}

// ---------------- CSR aggregation + bias + relu -> bf16 hi/lo H ----------------
__global__ __launch_bounds__(256) void agg_csr(const __half* __restrict__ XW,
    const int* __restrict__ rowstart, const int* __restrict__ esrc,
    const float* __restrict__ enorm, const float* __restrict__ dis,
    const float* __restrict__ bias,
    unsigned short* __restrict__ Hh, unsigned short* __restrict__ Hl, int n) {
  int w = (blockIdx.x * 256 + threadIdx.x) >> 6;
  int l = threadIdx.x & 63;
  if (w >= n) return;
  float dd = dis[w];
  float d2 = dd * dd;
  __half2 sh = ((const __half2*)(XW + (size_t)w * 128))[l];
  float2 A0 = make_float2(d2 * __low2float(sh), d2 * __high2float(sh));
  float2 A1 = make_float2(0.f, 0.f), A2 = make_float2(0.f, 0.f), A3 = make_float2(0.f, 0.f);
  int p = rowstart[w], p1 = rowstart[w + 1];
  for (; p + 4 <= p1; p += 4) {
    int s0 = esrc[p], s1 = esrc[p + 1], s2 = esrc[p + 2], s3 = esrc[p + 3];
    float w0 = enorm[p], w1 = enorm[p + 1], w2 = enorm[p + 2], w3 = enorm[p + 3];
    __half2 r0 = ((const __half2*)(XW + (size_t)s0 * 128))[l];
    __half2 r1 = ((const __half2*)(XW + (size_t)s1 * 128))[l];
    __half2 r2 = ((const __half2*)(XW + (size_t)s2 * 128))[l];
    __half2 r3 = ((const __half2*)(XW + (size_t)s3 * 128))[l];
    A0.x = fmaf(w0, __low2float(r0), A0.x); A0.y = fmaf(w0, __high2float(r0), A0.y);
    A1.x = fmaf(w1, __low2float(r1), A1.x); A1.y = fmaf(w1, __high2float(r1), A1.y);
    A2.x = fmaf(w2, __low2float(r2), A2.x); A2.y = fmaf(w2, __high2float(r2), A2.y);
    A3.x = fmaf(w3, __low2float(r3), A3.x); A3.y = fmaf(w3, __high2float(r3), A3.y);
  }
  for (; p < p1; ++p) {
    int s0 = esrc[p];
    float w0 = enorm[p];
    __half2 r0 = ((const __half2*)(XW + (size_t)s0 * 128))[l];
    A0.x = fmaf(w0, __low2float(r0), A0.x); A0.y = fmaf(w0, __high2float(r0), A0.y);
  }
  float2 b = ((const float2*)bias)[l];
  float vx = fmaxf(A0.x + A1.x + A2.x + A3.x + b.x, 0.f);
  float vy = fmaxf(A0.y + A1.y + A2.y + A3.y + b.y, 0.f);
  ushort2 oh, ol;
  oh.x = f2b(vx); ol.x = f2b(vx - b2f(oh.x));
  oh.y = f2b(vy); ol.y = f2b(vy - b2f(oh.y));
  ((ushort2*)(Hh + (size_t)w * 128))[l] = oh;
  ((ushort2*)(Hl + (size_t)w * 128))[l] = ol;
}

// ---------------- final layer ----------------
__global__ __launch_bounds__(256) void gemm_w8(const unsigned short* __restrict__ Hh,
    const unsigned short* __restrict__ Hl, const float* __restrict__ W8,
    float* __restrict__ XW2, int n) {
  __shared__ float w[256];
  int t = threadIdx.x;
  w[t] = W8[t];
  __syncthreads();
  int r = blockIdx.x * 256 + t;
  if (r >= n) return;
  const unsigned short* hh = Hh + (size_t)r * 128;
  const unsigned short* hl = Hl + (size_t)r * 128;
  float a0 = 0.f, a1 = 0.f;
#pragma unroll
  for (int k = 0; k < 128; k += 4) {
    ushort4 uh = *(const ushort4*)(hh + k);
    ushort4 ul = *(const ushort4*)(hl + k);
    float h0 = b2f(uh.x) + b2f(ul.x);
    float h1 = b2f(uh.y) + b2f(ul.y);
    float h2 = b2f(uh.z) + b2f(ul.z);
    float h3 = b2f(uh.w) + b2f(ul.w);
    a0 += h0 * w[2 * k + 0] + h1 * w[2 * k + 2] + h2 * w[2 * k + 4] + h3 * w[2 * k + 6];
    a1 += h0 * w[2 * k + 1] + h1 * w[2 * k + 3] + h2 * w[2 * k + 5] + h3 * w[2 * k + 7];
  }
  XW2[r * 2 + 0] = a0;
  XW2[r * 2 + 1] = a1;
}

__global__ __launch_bounds__(256) void agg_final(const float* __restrict__ XW2,
    const int* __restrict__ rowstart, const int* __restrict__ esrc,
    const float* __restrict__ enorm, const float* __restrict__ dis,
    const float* __restrict__ b8, float* __restrict__ out, int n) {
  int i = blockIdx.x * 256 + threadIdx.x;
  if (i >= n) return;
  float d = dis[i], d2 = d * d;
  float a0 = d2 * XW2[i * 2 + 0];
  float a1 = d2 * XW2[i * 2 + 1];
  int p1 = rowstart[i + 1];
  for (int p = rowstart[i]; p < p1; ++p) {
    int s = esrc[p];
    float wt = enorm[p];
    a0 = fmaf(wt, XW2[s * 2 + 0], a0);
    a1 = fmaf(wt, XW2[s * 2 + 1], a1);
  }
  out[i * 2 + 0] = a0 + b8[0];
  out[i * 2 + 1] = a1 + b8[1];
}

// ---------------- launcher ----------------
static inline char* alignp(char* p) {
  return (char*)(((uintptr_t)p + 255) & ~(uintptr_t)255);
}

extern "C" void kernel_launch(void* const* d_in, const int* in_sizes, int n_in,
                              void* d_out, int out_size, void* d_ws, size_t ws_size,
                              hipStream_t stream) {
  (void)in_sizes; (void)n_in; (void)out_size; (void)ws_size;
  const int n = NN, e = NE;
  const float* x  = (const float*)d_in[0];
  const int*   ei = (const int*)d_in[1];
  const float* ea = (const float*)d_in[2];
  const float* W1 = (const float*)d_in[3];
  const float* b1 = (const float*)d_in[4];
  const float* Wm = (const float*)d_in[5];
  const float* bm = (const float*)d_in[6];
  const float* W8 = (const float*)d_in[7];
  const float* b8 = (const float*)d_in[8];
  float* out = (float*)d_out;

  char* w = (char*)d_ws;
  int*   flag   = (int*)w;            w = alignp(w + 4);
  int*   part   = (int*)w;            w = alignp(w + SCAN_NB * 4);
  int*   partoff= (int*)w;            w = alignp(w + SCAN_NB * 4);
  unsigned long long* dc = (unsigned long long*)w; w = alignp(w + (size_t)n * 8);
  float* dis    = (float*)w;          w = alignp(w + (size_t)n * 4);
  int*   cnt    = (int*)w;            w = alignp(w + (size_t)n * 4);
  int*   cursor = (int*)w;            w = alignp(w + (size_t)n * 4);
  int*   rowst  = (int*)w;            w = alignp(w + (size_t)(n + 1) * 4);
  int*   esrc   = (int*)w;            w = alignp(w + (size_t)e * 4);
  float* enorm  = (float*)w;          w = alignp(w + (size_t)e * 4);
  unsigned short* Hh  = (unsigned short*)w;  w = alignp(w + (size_t)MP * 128 * 2);
  unsigned short* Hl  = (unsigned short*)w;  w = alignp(w + (size_t)MP * 128 * 2);
  unsigned short* Wth = (unsigned short*)w;  w = alignp(w + (size_t)7 * 16384 * 2);
  unsigned short* Wtl = (unsigned short*)w;  w = alignp(w + (size_t)7 * 16384 * 2);
  __half* XW  = (__half*)w;           w = alignp(w + (size_t)MP * 128 * 2);
  float* XW2  = (float*)w;            w = alignp(w + (size_t)MP * 2 * 4);

  const int GN = (n + 255) / 256;
  const int GE = (e + 255) / 256;

  detect_idx<<<1, 64, 0, stream>>>(ei, flag);
  prep_init<<<GN, 256, 0, stream>>>(dc, n);
  prep_hist<<<GE, 256, 0, stream>>>(ei, flag, ea, dc, e);
  prep_dis<<<GN, 256, 0, stream>>>(dc, dis, cnt, cursor, n);
  scan_part<<<SCAN_NB, 256, 0, stream>>>(cnt, part, n);
  scan_tops<<<1, 256, 0, stream>>>(part, partoff, rowst, n, e, SCAN_NB);
  scan_apply<<<SCAN_NB, 256, 0, stream>>>(cnt, partoff, rowst, n);
  prep_scatter<<<GE, 256, 0, stream>>>(ei, flag, ea, dis, rowst, cursor, esrc, enorm, e);
  cvt_x<<<(MP * 128 / 4 + 255) / 256, 256, 0, stream>>>(x, Hh, Hl, MP * 128, n * 128);
  cvt_w<<<(7 * 16384 + 255) / 256, 256, 0, stream>>>(W1, Wm, Wth, Wtl);

  for (int l = 0; l < 7; ++l) {
    const unsigned short* Bh = Wth + (size_t)l * 16384;
    const unsigned short* Bl = Wtl + (size_t)l * 16384;
    const float* bl = (l == 0) ? b1 : bm + (size_t)(l - 1) * 128;
    gemm_mfma<<<MP / 64, 256, 0, stream>>>(Hh, Hl, Bh, Bl, XW);
    agg_csr<<<(n * 64 + 255) / 256, 256, 0, stream>>>(XW, rowst, esrc, enorm, dis, bl, Hh, Hl, n);
  }
  gemm_w8<<<GN, 256, 0, stream>>>(Hh, Hl, W8, XW2, n);
  agg_final<<<GN, 256, 0, stream>>>(XW2, rowst, esrc, enorm, dis, b8, out, n);
}